// Round 17
// baseline (184.504 us; speedup 1.0000x reference)
//
#include <hip/hip_runtime.h>

typedef __fp16   pk16x2 __attribute__((ext_vector_type(2)));
typedef _Float16 f16x8 __attribute__((ext_vector_type(8)));
typedef float    f32x4  __attribute__((ext_vector_type(4)));
typedef float    f32x16 __attribute__((ext_vector_type(16)));

static constexpr int BSZ = 32768;
static constexpr int NB  = 8;
static constexpr int NW  = 256;
static constexpr int LW  = 64;
static constexpr int DF  = 512;
#define TAU   5.0f
#define LOG2E 1.44269504088896f
#define LN2   0.69314718055994f

union U2 { pk16x2 h; unsigned u; };
union U8 { f16x8 v; unsigned u[4]; };
union F4 { f32x4 v; float a[4]; };

__device__ inline unsigned pku(float a, float b) {
    U2 c; c.h = __builtin_amdgcn_cvt_pkrtz(a, b); return c.u;
}

// Lane32 exchange, R3-proven shfl_xor+cndmask form.
// (permlane32_swap: asm form miscompiled R4, builtin form -23us R16. Do not use.)
__device__ inline void xch32(float& a, float& b, int hi) {
    float snd = hi ? a : b;
    float rcv = __shfl_xor(snd, 32);
    float na = hi ? rcv : a;
    float nb = hi ? b : rcv;
    a = na; b = nb;
}

// ws layout (bytes): cbh fp16 [k][w][l] @0 (256K) | cbt fp16 [k][l][w] @256K (256K)
// | cc f32 [k][w] @512K (8K) | w1h fp16 [h][l] @520K (32K) | w2h fp16 [8][256] @552K (4K)
static constexpr size_t WS_CBH = 0;
static constexpr size_t WS_CBT = 262144;
static constexpr size_t WS_CC  = 524288;
static constexpr size_t WS_W1H = 532480;
static constexpr size_t WS_W2H = 565248;

// ---------------------------------------------------------------------------
// Prep: one-time fp32->fp16 conversion + transposes + ||c||^2. 9 blocks.
// ---------------------------------------------------------------------------
__global__ __launch_bounds__(256) void prep_kernel(
    const float* __restrict__ cb, const float* __restrict__ W1,
    const float* __restrict__ W2, char* __restrict__ ws)
{
    _Float16* cbh = (_Float16*)(ws + WS_CBH);
    _Float16* cbt = (_Float16*)(ws + WS_CBT);
    float*    cc  = (float*)   (ws + WS_CC);
    _Float16* w1h = (_Float16*)(ws + WS_W1H);
    _Float16* w2h = (_Float16*)(ws + WS_W2H);
    const int b = blockIdx.x, t = threadIdx.x;

    if (b < 8) {
        const float* src = cb + (size_t)t * DF + b * LW;
        float c_[64];
        #pragma unroll
        for (int i = 0; i < 16; ++i)
            *(f32x4*)&c_[i * 4] = *(const f32x4*)(src + i * 4);
        float s = 0.f;
        #pragma unroll
        for (int l = 0; l < 64; ++l) s += c_[l] * c_[l];
        cc[b * 256 + t] = s;
        #pragma unroll
        for (int c8 = 0; c8 < 8; ++c8) {
            U8 u;
            #pragma unroll
            for (int m = 0; m < 4; ++m)
                u.u[m] = pku(c_[c8 * 8 + 2 * m], c_[c8 * 8 + 2 * m + 1]);
            *(f16x8*)&cbh[((size_t)(b * 256 + t)) * 64 + c8 * 8] = u.v;
        }
        #pragma unroll
        for (int l = 0; l < 64; ++l)
            cbt[((size_t)(b * 64 + l)) * 256 + t] = (_Float16)c_[l];
    } else {
        float wv[64];
        #pragma unroll
        for (int l = 0; l < 64; ++l) wv[l] = W1[l * 256 + t];
        #pragma unroll
        for (int c8 = 0; c8 < 8; ++c8) {
            U8 u;
            #pragma unroll
            for (int m = 0; m < 4; ++m)
                u.u[m] = pku(wv[c8 * 8 + 2 * m], wv[c8 * 8 + 2 * m + 1]);
            *(f16x8*)&w1h[(size_t)t * 64 + c8 * 8] = u.v;
        }
        const int c = t >> 5, h0 = (t & 31) * 8;
        #pragma unroll
        for (int j = 0; j < 8; ++j)
            w2h[c * 256 + h0 + j] = (_Float16)W2[(h0 + j) * 8 + c];
    }
}

// ---------------------------------------------------------------------------
// Quant kernel: R15 structure. Change this round: f->out_f streaming copy in
// the staging window (short live range, 8 regs — avoids R14's trap), so the
// post-barrier x load hits L2 (~200cy vs ~900) and out_f stores hide under
// staging drain. grid (BSZ/128, NB), block 256, LDS 65KB -> 2 blk/CU
// (8 waves/CU = measured store-amplification optimum; do NOT raise).
// ---------------------------------------------------------------------------
__global__ __launch_bounds__(256, 2) void quant_kernel(
    const float* __restrict__ f, const char* __restrict__ ws,
    float* __restrict__ out_f, float* __restrict__ out_z,
    float* __restrict__ out_p)
{
    __shared__ _Float16 ct [NW * LW];    // [w][l], chunk s at s^(w&7)
    __shared__ _Float16 ctt[LW * NW];    // [l][w], chunk c at c^(l&7)
    __shared__ float    ccs[NW];

    const _Float16* cbh = (const _Float16*)(ws + WS_CBH);
    const _Float16* cbt = (const _Float16*)(ws + WS_CBT);
    const float*    ccw = (const float*)   (ws + WS_CC);

    const int k    = blockIdx.y;
    const int tid  = threadIdx.x;
    const int wid  = tid >> 6;
    const int lane = tid & 63;
    const int lr   = lane & 31;
    const int hi   = lane >> 5;
    const int r0   = blockIdx.x * 128;
    const int row  = r0 + wid * 32 + lr;

    // ---- stage ct + ctt from prep'd fp16 (coalesced 16B chunks) ----
    #pragma unroll
    for (int it = 0; it < 8; ++it) {
        int i = it * 256 + tid;           // ct chunk: w = i>>3, s = i&7
        int w = i >> 3, s = i & 7;
        f16x8 v = *(const f16x8*)(cbh + (size_t)k * 16384 + w * 64 + s * 8);
        *(f16x8*)&ct[w * 64 + (s ^ (w & 7)) * 8] = v;
    }
    #pragma unroll
    for (int it = 0; it < 8; ++it) {
        int i = it * 256 + tid;           // ctt chunk: l = i>>5, cw = i&31
        int l = i >> 5, cw = i & 31;
        f16x8 v = *(const f16x8*)(cbt + (size_t)k * 16384 + l * 256 + cw * 8);
        *(f16x8*)&ctt[l * 256 + (cw ^ (l & 7)) * 8] = v;
    }
    ccs[tid] = ccw[k * 256 + tid];

    // ---- f -> out_f streaming copy (short live range; hides under staging
    //      drain; warms L2 for the post-barrier x load) ----
    #pragma unroll
    for (int it = 0; it < 8; ++it) {
        int i = it * 256 + tid;           // 2048 f32x4 chunks: r = i>>4, c = i&15
        int r = i >> 4, c = i & 15;
        size_t off = (size_t)(r0 + r) * DF + k * LW + c * 4;
        *(f32x4*)(out_f + off) = *(const f32x4*)(f + off);
    }
    __syncthreads();
    // ---- no barriers below; waves independent ----

    // ---- x load (L2-hot after the copy above) ----
    float x_[32];
    {
        const float* fr = f + (size_t)row * DF + k * LW + hi * 8;
        #pragma unroll
        for (int i = 0; i < 8; ++i)
            *(f32x4*)&x_[i * 4] = *(const f32x4*)(fr + (i >> 1) * 16 + (i & 1) * 4);
    }
    f16x8 bxh[4];
    #pragma unroll
    for (int ks = 0; ks < 4; ++ks) {
        U8 uh;
        #pragma unroll
        for (int m = 0; m < 4; ++m)
            uh.u[m] = pku(x_[ks * 8 + 2 * m], x_[ks * 8 + 2 * m + 1]);
        bxh[ks] = uh.v;
    }

    // ---- distance GEMM (A from swizzled LDS) ----
    f32x16 acc[8];
    #pragma unroll
    for (int wt = 0; wt < 8; ++wt) acc[wt] = {};
    #pragma unroll
    for (int wt = 0; wt < 8; ++wt) {
        const int w = wt * 32 + lr;
        #pragma unroll
        for (int ks = 0; ks < 4; ++ks) {
            f16x8 a = *(const f16x8*)&ct[w * 64 + (((ks * 2 + hi) ^ (lr & 7))) * 8];
            acc[wt] = __builtin_amdgcn_mfma_f32_32x32x16_f16(a, bxh[ks], acc[wt], 0, 0, 0);
        }
    }

    // ---- softmax over 256 w ----
    const float KK = TAU * LOG2E;
    float mx = -1e30f;
    #pragma unroll
    for (int wt = 0; wt < 8; ++wt) {
        #pragma unroll
        for (int g = 0; g < 4; ++g) {
            F4 cc4; cc4.v = *(const f32x4*)&ccs[wt * 32 + g * 8 + hi * 4];
            #pragma unroll
            for (int j = 0; j < 4; ++j) {
                int q = g * 4 + j;
                float li = (2.f * acc[wt][q] - cc4.a[j]) * KK;
                acc[wt][q] = li;
                mx = fmaxf(mx, li);
            }
        }
    }
    mx = fmaxf(mx, __shfl_xor(mx, 32));
    float s = 0.f;
    #pragma unroll
    for (int wt = 0; wt < 8; ++wt) {
        #pragma unroll
        for (int q = 0; q < 16; ++q) {
            float e = __builtin_amdgcn_exp2f(acc[wt][q] - mx);
            acc[wt][q] = e; s += e;
        }
    }
    s += __shfl_xor(s, 32);
    const float inv = 1.f / s;
    #pragma unroll
    for (int wt = 0; wt < 8; ++wt) {
        #pragma unroll
        for (int q = 0; q < 16; ++q) acc[wt][q] *= inv;
    }

    // ---- z GEMM + p writeback (tight burst; B from LDS only) ----
    float* prow = out_p + (size_t)row * (NB * NW) + (size_t)k * NW + hi * 8;
    f32x16 zacc[2];
    zacc[0] = {}; zacc[1] = {};
    #pragma unroll
    for (int ks = 0; ks < 16; ++ks) {
        const int wt = ks >> 1;
        const int q0 = (ks & 1) * 8;
        float v[8];
        #pragma unroll
        for (int i = 0; i < 4; ++i) {
            float a0 = acc[wt][q0 + i];
            float a1 = acc[wt][q0 + 4 + i];
            xch32(a0, a1, hi);
            v[i] = a0; v[4 + i] = a1;
        }
        *(f32x4*)(prow + ks * 16)     = f32x4{v[0], v[1], v[2], v[3]};
        *(f32x4*)(prow + ks * 16 + 4) = f32x4{v[4], v[5], v[6], v[7]};
        U8 pa;
        pa.u[0] = pku(v[0], v[1]); pa.u[1] = pku(v[2], v[3]);
        pa.u[2] = pku(v[4], v[5]); pa.u[3] = pku(v[6], v[7]);
        #pragma unroll
        for (int nt = 0; nt < 2; ++nt) {
            f16x8 bz = *(const f16x8*)&ctt[(nt * 32 + lr) * 256 + (((ks * 2 + hi) ^ (lr & 7))) * 8];
            zacc[nt] = __builtin_amdgcn_mfma_f32_32x32x16_f16(pa.v, bz, zacc[nt], 0, 0, 0);
        }
    }
    const int rbase = r0 + wid * 32;
    #pragma unroll
    for (int nt = 0; nt < 2; ++nt) {
        #pragma unroll
        for (int q = 0; q < 16; ++q) {
            int rr = (q & 3) + 8 * (q >> 2) + 4 * hi;
            out_z[(size_t)(rbase + rr) * DF + k * LW + nt * 32 + lr] = zacc[nt][q];
        }
    }
}

// ---------------------------------------------------------------------------
// MLP kernel: R15-verbatim. grid (BSZ*NB/128), block 256, LDS 37KB,
// bounds(256,4) -> 16 waves/CU (measured win).
// ---------------------------------------------------------------------------
__global__ __launch_bounds__(256, 4) void mlp_kernel(
    const float* __restrict__ f, const char* __restrict__ ws,
    const float* __restrict__ b1, const float* __restrict__ b2,
    float* __restrict__ out_lg)
{
    __shared__ _Float16 w1t[NW * LW];    // [h][l], chunk s at s^(h&7)
    __shared__ _Float16 w2t[8 * NW];     // [m][h], chunk c at c^m
    __shared__ float    b1s[NW];

    const _Float16* w1h = (const _Float16*)(ws + WS_W1H);
    const _Float16* w2h = (const _Float16*)(ws + WS_W2H);

    const int tid  = threadIdx.x;
    const int wid  = tid >> 6;
    const int lane = tid & 63;
    const int lr   = lane & 31;
    const int hi   = lane >> 5;
    const int m0   = blockIdx.x * 128;
    const int m    = m0 + wid * 32 + lr;      // this lane's f_split row

    // ---- staging ----
    #pragma unroll
    for (int it = 0; it < 8; ++it) {
        int i = it * 256 + tid;           // w1t chunk: h = i>>3, s = i&7
        int h = i >> 3, s = i & 7;
        f16x8 v = *(const f16x8*)(w1h + h * 64 + s * 8);
        *(f16x8*)&w1t[h * 64 + (s ^ (h & 7)) * 8] = v;
    }
    {
        int mm = tid >> 5, c = tid & 31;  // w2t: 256 chunks
        f16x8 v = *(const f16x8*)(w2h + mm * 256 + c * 8);
        *(f16x8*)&w2t[mm * 256 + (c ^ mm) * 8] = v;
    }
    b1s[tid] = b1[tid];
    __syncthreads();

    // ---- x fragment load ----
    float x_[32];
    {
        const float* fr = f + (size_t)m * LW + hi * 8;
        #pragma unroll
        for (int i = 0; i < 8; ++i)
            *(f32x4*)&x_[i * 4] = *(const f32x4*)(fr + (i >> 1) * 16 + (i & 1) * 4);
    }
    f16x8 bxh[4];
    #pragma unroll
    for (int ks = 0; ks < 4; ++ks) {
        U8 uh;
        #pragma unroll
        for (int mm = 0; mm < 4; ++mm)
            uh.u[mm] = pku(x_[ks * 8 + 2 * mm], x_[ks * 8 + 2 * mm + 1]);
        bxh[ks] = uh.v;
    }

    // ---- G1 (streaming per-ht) -> pack -> G2 ----
    f32x16 acc2 = {};
    #pragma unroll
    for (int ht = 0; ht < 8; ++ht) {
        f32x16 a1 = {};
        #pragma unroll
        for (int ks = 0; ks < 4; ++ks) {
            f16x8 a = *(const f16x8*)&w1t[(ht * 32 + lr) * 64 + (((ks * 2 + hi) ^ (lr & 7))) * 8];
            a1 = __builtin_amdgcn_mfma_f32_32x32x16_f16(a, bxh[ks], a1, 0, 0, 0);
        }
        float hv[16];
        #pragma unroll
        for (int g = 0; g < 4; ++g) {
            F4 b4; b4.v = *(const f32x4*)&b1s[ht * 32 + g * 8 + hi * 4];
            #pragma unroll
            for (int j = 0; j < 4; ++j) {
                int q = g * 4 + j;
                hv[q] = fmaxf(a1[q] + b4.a[j], 0.f);
            }
        }
        #pragma unroll
        for (int half = 0; half < 2; ++half) {
            const int ks = 2 * ht + half;
            const int q0 = half * 8;
            float v[8];
            #pragma unroll
            for (int i = 0; i < 4; ++i) {
                float a0 = hv[q0 + i];
                float a1v = hv[q0 + 4 + i];
                xch32(a0, a1v, hi);
                v[i] = a0; v[4 + i] = a1v;
            }
            U8 hb;
            hb.u[0] = pku(v[0], v[1]); hb.u[1] = pku(v[2], v[3]);
            hb.u[2] = pku(v[4], v[5]); hb.u[3] = pku(v[6], v[7]);
            f16x8 aw2 = *(const f16x8*)&w2t[(lr & 7) * 256 + (((ks * 2 + hi) ^ (lr & 7))) * 8];
            acc2 = __builtin_amdgcn_mfma_f32_32x32x16_f16(aw2, hb.v, acc2, 0, 0, 0);
        }
    }

    // ---- log_softmax over 8 classes (regs q=0..3 hold classes q+4*hi) ----
    F4 b2v; b2v.v = *(const f32x4*)(b2 + hi * 4);
    float lg[4];
    #pragma unroll
    for (int q = 0; q < 4; ++q) lg[q] = acc2[q] + b2v.a[q];
    float mm = fmaxf(fmaxf(lg[0], lg[1]), fmaxf(lg[2], lg[3]));
    mm = fmaxf(mm, __shfl_xor(mm, 32));
    float se = 0.f;
    #pragma unroll
    for (int q = 0; q < 4; ++q) se += __builtin_amdgcn_exp2f((lg[q] - mm) * LOG2E);
    se += __shfl_xor(se, 32);
    float lse = mm + __builtin_amdgcn_logf(se) * LN2;
    *(f32x4*)(out_lg + (size_t)m * 8 + hi * 4) =
        f32x4{lg[0] - lse, lg[1] - lse, lg[2] - lse, lg[3] - lse};
}

extern "C" void kernel_launch(void* const* d_in, const int* in_sizes, int n_in,
                              void* d_out, int out_size, void* d_ws, size_t ws_size,
                              hipStream_t stream) {
    const float* f  = (const float*)d_in[0];
    const float* cb = (const float*)d_in[1];
    const float* W1 = (const float*)d_in[2];
    const float* b1 = (const float*)d_in[3];
    const float* W2 = (const float*)d_in[4];
    const float* b2 = (const float*)d_in[5];

    float* out    = (float*)d_out;
    float* out_f  = out;
    float* out_z  = out_f + (size_t)BSZ * DF;
    float* out_p  = out_z + (size_t)BSZ * DF;
    float* out_lg = out_p + (size_t)BSZ * NB * NW;

    hipLaunchKernelGGL(prep_kernel, dim3(9), dim3(256), 0, stream,
                       cb, W1, W2, (char*)d_ws);
    hipLaunchKernelGGL(quant_kernel, dim3(BSZ / 128, NB), dim3(256), 0, stream,
                       f, (const char*)d_ws, out_f, out_z, out_p);
    hipLaunchKernelGGL(mlp_kernel, dim3(BSZ * NB / 128), dim3(256), 0, stream,
                       f, (const char*)d_ws, b1, b2, out_lg);
}

// Round 18
// 154.825 us; speedup vs baseline: 1.1917x; 1.1917x over previous
//
#include <hip/hip_runtime.h>

typedef __fp16   pk16x2 __attribute__((ext_vector_type(2)));
typedef _Float16 f16x8 __attribute__((ext_vector_type(8)));
typedef float    f32x4  __attribute__((ext_vector_type(4)));
typedef float    f32x16 __attribute__((ext_vector_type(16)));

static constexpr int BSZ = 32768;
static constexpr int NB  = 8;
static constexpr int NW  = 256;
static constexpr int LW  = 64;
static constexpr int DF  = 512;
#define TAU   5.0f
#define LOG2E 1.44269504088896f
#define LN2   0.69314718055994f

union U2 { pk16x2 h; unsigned u; };
union U8 { f16x8 v; unsigned u[4]; };
union F4 { f32x4 v; float a[4]; };

__device__ inline unsigned pku(float a, float b) {
    U2 c; c.h = __builtin_amdgcn_cvt_pkrtz(a, b); return c.u;
}

// Lane32 exchange, R3-proven shfl_xor+cndmask form.
// (permlane32_swap: asm form miscompiled R4, builtin form -23us R16. Do not use.)
__device__ inline void xch32(float& a, float& b, int hi) {
    float snd = hi ? a : b;
    float rcv = __shfl_xor(snd, 32);
    float na = hi ? rcv : a;
    float nb = hi ? b : rcv;
    a = na; b = nb;
}

// ws layout (bytes): cbh fp16 [k][w][l] @0 (256K) | cbt fp16 [k][l][w] @256K (256K)
// | cck f32 [k][w] @512K (8K, = ||c||^2 * TAU * LOG2E premultiplied)
// | w1h fp16 [h][l] @520K (32K) | w2h fp16 [8][256] @552K (4K)
static constexpr size_t WS_CBH = 0;
static constexpr size_t WS_CBT = 262144;
static constexpr size_t WS_CC  = 524288;
static constexpr size_t WS_W1H = 532480;
static constexpr size_t WS_W2H = 565248;

// ---------------------------------------------------------------------------
// Prep: one-time fp32->fp16 conversion + transposes + ||c||^2*TAU*LOG2E.
// ---------------------------------------------------------------------------
__global__ __launch_bounds__(256) void prep_kernel(
    const float* __restrict__ cb, const float* __restrict__ W1,
    const float* __restrict__ W2, char* __restrict__ ws)
{
    _Float16* cbh = (_Float16*)(ws + WS_CBH);
    _Float16* cbt = (_Float16*)(ws + WS_CBT);
    float*    cc  = (float*)   (ws + WS_CC);
    _Float16* w1h = (_Float16*)(ws + WS_W1H);
    _Float16* w2h = (_Float16*)(ws + WS_W2H);
    const int b = blockIdx.x, t = threadIdx.x;

    if (b < 8) {
        const float* src = cb + (size_t)t * DF + b * LW;
        float c_[64];
        #pragma unroll
        for (int i = 0; i < 16; ++i)
            *(f32x4*)&c_[i * 4] = *(const f32x4*)(src + i * 4);
        float s = 0.f;
        #pragma unroll
        for (int l = 0; l < 64; ++l) s += c_[l] * c_[l];
        cc[b * 256 + t] = s * (TAU * LOG2E);   // premultiplied for the fma logit
        #pragma unroll
        for (int c8 = 0; c8 < 8; ++c8) {
            U8 u;
            #pragma unroll
            for (int m = 0; m < 4; ++m)
                u.u[m] = pku(c_[c8 * 8 + 2 * m], c_[c8 * 8 + 2 * m + 1]);
            *(f16x8*)&cbh[((size_t)(b * 256 + t)) * 64 + c8 * 8] = u.v;
        }
        #pragma unroll
        for (int l = 0; l < 64; ++l)
            cbt[((size_t)(b * 64 + l)) * 256 + t] = (_Float16)c_[l];
    } else {
        float wv[64];
        #pragma unroll
        for (int l = 0; l < 64; ++l) wv[l] = W1[l * 256 + t];
        #pragma unroll
        for (int c8 = 0; c8 < 8; ++c8) {
            U8 u;
            #pragma unroll
            for (int m = 0; m < 4; ++m)
                u.u[m] = pku(wv[c8 * 8 + 2 * m], wv[c8 * 8 + 2 * m + 1]);
            *(f16x8*)&w1h[(size_t)t * 64 + c8 * 8] = u.v;
        }
        const int c = t >> 5, h0 = (t & 31) * 8;
        #pragma unroll
        for (int j = 0; j < 8; ++j)
            w2h[c * 256 + h0 + j] = (_Float16)W2[(h0 + j) * 8 + c];
    }
}

// ---------------------------------------------------------------------------
// Quant kernel: R15 structure; this round's change is softmax-only:
// no-max exp2 (|logit| <= ~15 by bound analysis: ||c||<=0.29, x~N(0,1) ->
// exp2 range safe by 110+ bits of margin), one-fma logit via premultiplied
// cck, and 1/s folded into the z-loop's post-exchange v[] (inv identical
// across the hi-pair: both lanes hold the same batch row, col=lane&31).
// grid (BSZ/128, NB), block 256, LDS 65KB -> 2 blk/CU (8 waves/CU =
// measured store-amplification optimum; do NOT raise).
// ---------------------------------------------------------------------------
__global__ __launch_bounds__(256, 2) void quant_kernel(
    const float* __restrict__ f, const char* __restrict__ ws,
    float* __restrict__ out_f, float* __restrict__ out_z,
    float* __restrict__ out_p)
{
    __shared__ _Float16 ct [NW * LW];    // [w][l], chunk s at s^(w&7)
    __shared__ _Float16 ctt[LW * NW];    // [l][w], chunk c at c^(l&7)
    __shared__ float    ccs[NW];         // ||c||^2 * TAU * LOG2E

    const _Float16* cbh = (const _Float16*)(ws + WS_CBH);
    const _Float16* cbt = (const _Float16*)(ws + WS_CBT);
    const float*    ccw = (const float*)   (ws + WS_CC);

    const int k    = blockIdx.y;
    const int tid  = threadIdx.x;
    const int wid  = tid >> 6;
    const int lane = tid & 63;
    const int lr   = lane & 31;
    const int hi   = lane >> 5;
    const int r0   = blockIdx.x * 128;
    const int row  = r0 + wid * 32 + lr;

    // ---- stage ct + ctt from prep'd fp16 (coalesced 16B chunks) ----
    #pragma unroll
    for (int it = 0; it < 8; ++it) {
        int i = it * 256 + tid;           // ct chunk: w = i>>3, s = i&7
        int w = i >> 3, s = i & 7;
        f16x8 v = *(const f16x8*)(cbh + (size_t)k * 16384 + w * 64 + s * 8);
        *(f16x8*)&ct[w * 64 + (s ^ (w & 7)) * 8] = v;
    }
    #pragma unroll
    for (int it = 0; it < 8; ++it) {
        int i = it * 256 + tid;           // ctt chunk: l = i>>5, cw = i&31
        int l = i >> 5, cw = i & 31;
        f16x8 v = *(const f16x8*)(cbt + (size_t)k * 16384 + l * 256 + cw * 8);
        *(f16x8*)&ctt[l * 256 + (cw ^ (l & 7)) * 8] = v;
    }
    ccs[tid] = ccw[k * 256 + tid];
    __syncthreads();
    // ---- no barriers below; waves independent ----

    // ---- x load + out_f passthrough ----
    float x_[32];
    {
        const float* fr = f     + (size_t)row * DF + k * LW + hi * 8;
        float*       fo = out_f + (size_t)row * DF + k * LW + hi * 8;
        #pragma unroll
        for (int i = 0; i < 8; ++i) {
            f32x4 v = *(const f32x4*)(fr + (i >> 1) * 16 + (i & 1) * 4);
            *(f32x4*)&x_[i * 4] = v;
            *(f32x4*)(fo + (i >> 1) * 16 + (i & 1) * 4) = v;
        }
    }
    f16x8 bxh[4];
    #pragma unroll
    for (int ks = 0; ks < 4; ++ks) {
        U8 uh;
        #pragma unroll
        for (int m = 0; m < 4; ++m)
            uh.u[m] = pku(x_[ks * 8 + 2 * m], x_[ks * 8 + 2 * m + 1]);
        bxh[ks] = uh.v;
    }

    // ---- distance GEMM (A from swizzled LDS) ----
    f32x16 acc[8];
    #pragma unroll
    for (int wt = 0; wt < 8; ++wt) acc[wt] = {};
    #pragma unroll
    for (int wt = 0; wt < 8; ++wt) {
        const int w = wt * 32 + lr;
        #pragma unroll
        for (int ks = 0; ks < 4; ++ks) {
            f16x8 a = *(const f16x8*)&ct[w * 64 + (((ks * 2 + hi) ^ (lr & 7))) * 8];
            acc[wt] = __builtin_amdgcn_mfma_f32_32x32x16_f16(a, bxh[ks], acc[wt], 0, 0, 0);
        }
    }

    // ---- softmax over 256 w: NO-MAX exp2 (safe by logit bound), 1 fma/elem ----
    const float KK2 = 2.0f * TAU * LOG2E;
    float s = 0.f;
    #pragma unroll
    for (int wt = 0; wt < 8; ++wt) {
        #pragma unroll
        for (int g = 0; g < 4; ++g) {
            F4 cc4; cc4.v = *(const f32x4*)&ccs[wt * 32 + g * 8 + hi * 4];
            #pragma unroll
            for (int j = 0; j < 4; ++j) {
                int q = g * 4 + j;
                float e = __builtin_amdgcn_exp2f(__builtin_fmaf(acc[wt][q], KK2, -cc4.a[j]));
                acc[wt][q] = e;
                s += e;
            }
        }
    }
    s += __shfl_xor(s, 32);
    const float inv = 1.f / s;           // folded into v[] in the z-loop

    // ---- z GEMM + p writeback (tight burst; B from LDS only) ----
    float* prow = out_p + (size_t)row * (NB * NW) + (size_t)k * NW + hi * 8;
    f32x16 zacc[2];
    zacc[0] = {}; zacc[1] = {};
    #pragma unroll
    for (int ks = 0; ks < 16; ++ks) {
        const int wt = ks >> 1;
        const int q0 = (ks & 1) * 8;
        float v[8];
        #pragma unroll
        for (int i = 0; i < 4; ++i) {
            float a0 = acc[wt][q0 + i];
            float a1 = acc[wt][q0 + 4 + i];
            xch32(a0, a1, hi);
            v[i]     = a0 * inv;          // normalization folded here
            v[4 + i] = a1 * inv;
        }
        *(f32x4*)(prow + ks * 16)     = f32x4{v[0], v[1], v[2], v[3]};
        *(f32x4*)(prow + ks * 16 + 4) = f32x4{v[4], v[5], v[6], v[7]};
        U8 pa;
        pa.u[0] = pku(v[0], v[1]); pa.u[1] = pku(v[2], v[3]);
        pa.u[2] = pku(v[4], v[5]); pa.u[3] = pku(v[6], v[7]);
        #pragma unroll
        for (int nt = 0; nt < 2; ++nt) {
            f16x8 bz = *(const f16x8*)&ctt[(nt * 32 + lr) * 256 + (((ks * 2 + hi) ^ (lr & 7))) * 8];
            zacc[nt] = __builtin_amdgcn_mfma_f32_32x32x16_f16(pa.v, bz, zacc[nt], 0, 0, 0);
        }
    }
    const int rbase = r0 + wid * 32;
    #pragma unroll
    for (int nt = 0; nt < 2; ++nt) {
        #pragma unroll
        for (int q = 0; q < 16; ++q) {
            int rr = (q & 3) + 8 * (q >> 2) + 4 * hi;
            out_z[(size_t)(rbase + rr) * DF + k * LW + nt * 32 + lr] = zacc[nt][q];
        }
    }
}

// ---------------------------------------------------------------------------
// MLP kernel: R15-verbatim. grid (BSZ*NB/128), block 256, LDS 37KB,
// bounds(256,4) -> 16 waves/CU (measured win).
// ---------------------------------------------------------------------------
__global__ __launch_bounds__(256, 4) void mlp_kernel(
    const float* __restrict__ f, const char* __restrict__ ws,
    const float* __restrict__ b1, const float* __restrict__ b2,
    float* __restrict__ out_lg)
{
    __shared__ _Float16 w1t[NW * LW];    // [h][l], chunk s at s^(h&7)
    __shared__ _Float16 w2t[8 * NW];     // [m][h], chunk c at c^m
    __shared__ float    b1s[NW];

    const _Float16* w1h = (const _Float16*)(ws + WS_W1H);
    const _Float16* w2h = (const _Float16*)(ws + WS_W2H);

    const int tid  = threadIdx.x;
    const int wid  = tid >> 6;
    const int lane = tid & 63;
    const int lr   = lane & 31;
    const int hi   = lane >> 5;
    const int m0   = blockIdx.x * 128;
    const int m    = m0 + wid * 32 + lr;      // this lane's f_split row

    // ---- staging ----
    #pragma unroll
    for (int it = 0; it < 8; ++it) {
        int i = it * 256 + tid;           // w1t chunk: h = i>>3, s = i&7
        int h = i >> 3, s = i & 7;
        f16x8 v = *(const f16x8*)(w1h + h * 64 + s * 8);
        *(f16x8*)&w1t[h * 64 + (s ^ (h & 7)) * 8] = v;
    }
    {
        int mm = tid >> 5, c = tid & 31;  // w2t: 256 chunks
        f16x8 v = *(const f16x8*)(w2h + mm * 256 + c * 8);
        *(f16x8*)&w2t[mm * 256 + (c ^ mm) * 8] = v;
    }
    b1s[tid] = b1[tid];
    __syncthreads();

    // ---- x fragment load ----
    float x_[32];
    {
        const float* fr = f + (size_t)m * LW + hi * 8;
        #pragma unroll
        for (int i = 0; i < 8; ++i)
            *(f32x4*)&x_[i * 4] = *(const f32x4*)(fr + (i >> 1) * 16 + (i & 1) * 4);
    }
    f16x8 bxh[4];
    #pragma unroll
    for (int ks = 0; ks < 4; ++ks) {
        U8 uh;
        #pragma unroll
        for (int mm = 0; mm < 4; ++mm)
            uh.u[mm] = pku(x_[ks * 8 + 2 * mm], x_[ks * 8 + 2 * mm + 1]);
        bxh[ks] = uh.v;
    }

    // ---- G1 (streaming per-ht) -> pack -> G2 ----
    f32x16 acc2 = {};
    #pragma unroll
    for (int ht = 0; ht < 8; ++ht) {
        f32x16 a1 = {};
        #pragma unroll
        for (int ks = 0; ks < 4; ++ks) {
            f16x8 a = *(const f16x8*)&w1t[(ht * 32 + lr) * 64 + (((ks * 2 + hi) ^ (lr & 7))) * 8];
            a1 = __builtin_amdgcn_mfma_f32_32x32x16_f16(a, bxh[ks], a1, 0, 0, 0);
        }
        float hv[16];
        #pragma unroll
        for (int g = 0; g < 4; ++g) {
            F4 b4; b4.v = *(const f32x4*)&b1s[ht * 32 + g * 8 + hi * 4];
            #pragma unroll
            for (int j = 0; j < 4; ++j) {
                int q = g * 4 + j;
                hv[q] = fmaxf(a1[q] + b4.a[j], 0.f);
            }
        }
        #pragma unroll
        for (int half = 0; half < 2; ++half) {
            const int ks = 2 * ht + half;
            const int q0 = half * 8;
            float v[8];
            #pragma unroll
            for (int i = 0; i < 4; ++i) {
                float a0 = hv[q0 + i];
                float a1v = hv[q0 + 4 + i];
                xch32(a0, a1v, hi);
                v[i] = a0; v[4 + i] = a1v;
            }
            U8 hb;
            hb.u[0] = pku(v[0], v[1]); hb.u[1] = pku(v[2], v[3]);
            hb.u[2] = pku(v[4], v[5]); hb.u[3] = pku(v[6], v[7]);
            f16x8 aw2 = *(const f16x8*)&w2t[(lr & 7) * 256 + (((ks * 2 + hi) ^ (lr & 7))) * 8];
            acc2 = __builtin_amdgcn_mfma_f32_32x32x16_f16(aw2, hb.v, acc2, 0, 0, 0);
        }
    }

    // ---- log_softmax over 8 classes (regs q=0..3 hold classes q+4*hi) ----
    F4 b2v; b2v.v = *(const f32x4*)(b2 + hi * 4);
    float lg[4];
    #pragma unroll
    for (int q = 0; q < 4; ++q) lg[q] = acc2[q] + b2v.a[q];
    float mm = fmaxf(fmaxf(lg[0], lg[1]), fmaxf(lg[2], lg[3]));
    mm = fmaxf(mm, __shfl_xor(mm, 32));
    float se = 0.f;
    #pragma unroll
    for (int q = 0; q < 4; ++q) se += __builtin_amdgcn_exp2f((lg[q] - mm) * LOG2E);
    se += __shfl_xor(se, 32);
    float lse = mm + __builtin_amdgcn_logf(se) * LN2;
    *(f32x4*)(out_lg + (size_t)m * 8 + hi * 4) =
        f32x4{lg[0] - lse, lg[1] - lse, lg[2] - lse, lg[3] - lse};
}

extern "C" void kernel_launch(void* const* d_in, const int* in_sizes, int n_in,
                              void* d_out, int out_size, void* d_ws, size_t ws_size,
                              hipStream_t stream) {
    const float* f  = (const float*)d_in[0];
    const float* cb = (const float*)d_in[1];
    const float* W1 = (const float*)d_in[2];
    const float* b1 = (const float*)d_in[3];
    const float* W2 = (const float*)d_in[4];
    const float* b2 = (const float*)d_in[5];

    float* out    = (float*)d_out;
    float* out_f  = out;
    float* out_z  = out_f + (size_t)BSZ * DF;
    float* out_p  = out_z + (size_t)BSZ * DF;
    float* out_lg = out_p + (size_t)BSZ * NB * NW;

    hipLaunchKernelGGL(prep_kernel, dim3(9), dim3(256), 0, stream,
                       cb, W1, W2, (char*)d_ws);
    hipLaunchKernelGGL(quant_kernel, dim3(BSZ / 128, NB), dim3(256), 0, stream,
                       f, (const char*)d_ws, out_f, out_z, out_p);
    hipLaunchKernelGGL(mlp_kernel, dim3(BSZ * NB / 128), dim3(256), 0, stream,
                       f, (const char*)d_ws, b1, b2, out_lg);
}

// Round 19
// 145.684 us; speedup vs baseline: 1.2665x; 1.0627x over previous
//
#include <hip/hip_runtime.h>

typedef __fp16   pk16x2 __attribute__((ext_vector_type(2)));
typedef _Float16 f16x8 __attribute__((ext_vector_type(8)));
typedef float    f32x4  __attribute__((ext_vector_type(4)));
typedef float    f32x16 __attribute__((ext_vector_type(16)));

static constexpr int BSZ = 32768;
static constexpr int NB  = 8;
static constexpr int NW  = 256;
static constexpr int LW  = 64;
static constexpr int DF  = 512;
#define TAU   5.0f
#define LOG2E 1.44269504088896f
#define LN2   0.69314718055994f

union U2 { pk16x2 h; unsigned u; };
union U8 { f16x8 v; unsigned u[4]; };
union F4 { f32x4 v; float a[4]; };

__device__ inline unsigned pku(float a, float b) {
    U2 c; c.h = __builtin_amdgcn_cvt_pkrtz(a, b); return c.u;
}

// Lane32 exchange, R3-proven shfl_xor+cndmask form.
// (permlane32_swap: asm form miscompiled R4, builtin form -23us R16. Do not use.)
__device__ inline void xch32(float& a, float& b, int hi) {
    float snd = hi ? a : b;
    float rcv = __shfl_xor(snd, 32);
    float na = hi ? rcv : a;
    float nb = hi ? b : rcv;
    a = na; b = nb;
}

// ws layout (bytes): cbh fp16 [k][w][l] @0 (256K) | cbt fp16 [k][l][w] @256K (256K)
// | cc f32 [k][w] @512K (8K) | w1h fp16 [h][l] @520K (32K) | w2h fp16 [8][256] @552K (4K)
static constexpr size_t WS_CBH = 0;
static constexpr size_t WS_CBT = 262144;
static constexpr size_t WS_CC  = 524288;
static constexpr size_t WS_W1H = 532480;
static constexpr size_t WS_W2H = 565248;

// ---------------------------------------------------------------------------
// Prep: one-time fp32->fp16 conversion + transposes + ||c||^2. 9 blocks.
// ---------------------------------------------------------------------------
__global__ __launch_bounds__(256) void prep_kernel(
    const float* __restrict__ cb, const float* __restrict__ W1,
    const float* __restrict__ W2, char* __restrict__ ws)
{
    _Float16* cbh = (_Float16*)(ws + WS_CBH);
    _Float16* cbt = (_Float16*)(ws + WS_CBT);
    float*    cc  = (float*)   (ws + WS_CC);
    _Float16* w1h = (_Float16*)(ws + WS_W1H);
    _Float16* w2h = (_Float16*)(ws + WS_W2H);
    const int b = blockIdx.x, t = threadIdx.x;

    if (b < 8) {
        const float* src = cb + (size_t)t * DF + b * LW;
        float c_[64];
        #pragma unroll
        for (int i = 0; i < 16; ++i)
            *(f32x4*)&c_[i * 4] = *(const f32x4*)(src + i * 4);
        float s = 0.f;
        #pragma unroll
        for (int l = 0; l < 64; ++l) s += c_[l] * c_[l];
        cc[b * 256 + t] = s;
        #pragma unroll
        for (int c8 = 0; c8 < 8; ++c8) {
            U8 u;
            #pragma unroll
            for (int m = 0; m < 4; ++m)
                u.u[m] = pku(c_[c8 * 8 + 2 * m], c_[c8 * 8 + 2 * m + 1]);
            *(f16x8*)&cbh[((size_t)(b * 256 + t)) * 64 + c8 * 8] = u.v;
        }
        #pragma unroll
        for (int l = 0; l < 64; ++l)
            cbt[((size_t)(b * 64 + l)) * 256 + t] = (_Float16)c_[l];
    } else {
        float wv[64];
        #pragma unroll
        for (int l = 0; l < 64; ++l) wv[l] = W1[l * 256 + t];
        #pragma unroll
        for (int c8 = 0; c8 < 8; ++c8) {
            U8 u;
            #pragma unroll
            for (int m = 0; m < 4; ++m)
                u.u[m] = pku(wv[c8 * 8 + 2 * m], wv[c8 * 8 + 2 * m + 1]);
            *(f16x8*)&w1h[(size_t)t * 64 + c8 * 8] = u.v;
        }
        const int c = t >> 5, h0 = (t & 31) * 8;
        #pragma unroll
        for (int j = 0; j < 8; ++j)
            w2h[c * 256 + h0 + j] = (_Float16)W2[(h0 + j) * 8 + c];
    }
}

// ---------------------------------------------------------------------------
// Quant kernel: R15-VERBATIM (best measured: 152.0us total). grid (BSZ/128,
// NB), block 256, LDS 65KB -> 2 blk/CU (8 waves/CU = measured
// store-amplification optimum). Phase order locked (R14/R17 regressions).
// ---------------------------------------------------------------------------
__global__ __launch_bounds__(256, 2) void quant_kernel(
    const float* __restrict__ f, const char* __restrict__ ws,
    float* __restrict__ out_f, float* __restrict__ out_z,
    float* __restrict__ out_p)
{
    __shared__ _Float16 ct [NW * LW];    // [w][l], chunk s at s^(w&7)
    __shared__ _Float16 ctt[LW * NW];    // [l][w], chunk c at c^(l&7)
    __shared__ float    ccs[NW];

    const _Float16* cbh = (const _Float16*)(ws + WS_CBH);
    const _Float16* cbt = (const _Float16*)(ws + WS_CBT);
    const float*    ccw = (const float*)   (ws + WS_CC);

    const int k    = blockIdx.y;
    const int tid  = threadIdx.x;
    const int wid  = tid >> 6;
    const int lane = tid & 63;
    const int lr   = lane & 31;
    const int hi   = lane >> 5;
    const int r0   = blockIdx.x * 128;
    const int row  = r0 + wid * 32 + lr;

    // ---- stage ct + ctt from prep'd fp16 (coalesced 16B chunks) ----
    #pragma unroll
    for (int it = 0; it < 8; ++it) {
        int i = it * 256 + tid;           // ct chunk: w = i>>3, s = i&7
        int w = i >> 3, s = i & 7;
        f16x8 v = *(const f16x8*)(cbh + (size_t)k * 16384 + w * 64 + s * 8);
        *(f16x8*)&ct[w * 64 + (s ^ (w & 7)) * 8] = v;
    }
    #pragma unroll
    for (int it = 0; it < 8; ++it) {
        int i = it * 256 + tid;           // ctt chunk: l = i>>5, cw = i&31
        int l = i >> 5, cw = i & 31;
        f16x8 v = *(const f16x8*)(cbt + (size_t)k * 16384 + l * 256 + cw * 8);
        *(f16x8*)&ctt[l * 256 + (cw ^ (l & 7)) * 8] = v;
    }
    ccs[tid] = ccw[k * 256 + tid];
    __syncthreads();
    // ---- no barriers below; waves independent ----

    // ---- x load + out_f passthrough (L3-hot: mlp ran first) ----
    float x_[32];
    {
        const float* fr = f     + (size_t)row * DF + k * LW + hi * 8;
        float*       fo = out_f + (size_t)row * DF + k * LW + hi * 8;
        #pragma unroll
        for (int i = 0; i < 8; ++i) {
            f32x4 v = *(const f32x4*)(fr + (i >> 1) * 16 + (i & 1) * 4);
            *(f32x4*)&x_[i * 4] = v;
            *(f32x4*)(fo + (i >> 1) * 16 + (i & 1) * 4) = v;
        }
    }
    f16x8 bxh[4];
    #pragma unroll
    for (int ks = 0; ks < 4; ++ks) {
        U8 uh;
        #pragma unroll
        for (int m = 0; m < 4; ++m)
            uh.u[m] = pku(x_[ks * 8 + 2 * m], x_[ks * 8 + 2 * m + 1]);
        bxh[ks] = uh.v;
    }

    // ---- distance GEMM (A from swizzled LDS) ----
    f32x16 acc[8];
    #pragma unroll
    for (int wt = 0; wt < 8; ++wt) acc[wt] = {};
    #pragma unroll
    for (int wt = 0; wt < 8; ++wt) {
        const int w = wt * 32 + lr;
        #pragma unroll
        for (int ks = 0; ks < 4; ++ks) {
            f16x8 a = *(const f16x8*)&ct[w * 64 + (((ks * 2 + hi) ^ (lr & 7))) * 8];
            acc[wt] = __builtin_amdgcn_mfma_f32_32x32x16_f16(a, bxh[ks], acc[wt], 0, 0, 0);
        }
    }

    // ---- softmax over 256 w ----
    const float KK = TAU * LOG2E;
    float mx = -1e30f;
    #pragma unroll
    for (int wt = 0; wt < 8; ++wt) {
        #pragma unroll
        for (int g = 0; g < 4; ++g) {
            F4 cc4; cc4.v = *(const f32x4*)&ccs[wt * 32 + g * 8 + hi * 4];
            #pragma unroll
            for (int j = 0; j < 4; ++j) {
                int q = g * 4 + j;
                float li = (2.f * acc[wt][q] - cc4.a[j]) * KK;
                acc[wt][q] = li;
                mx = fmaxf(mx, li);
            }
        }
    }
    mx = fmaxf(mx, __shfl_xor(mx, 32));
    float s = 0.f;
    #pragma unroll
    for (int wt = 0; wt < 8; ++wt) {
        #pragma unroll
        for (int q = 0; q < 16; ++q) {
            float e = __builtin_amdgcn_exp2f(acc[wt][q] - mx);
            acc[wt][q] = e; s += e;
        }
    }
    s += __shfl_xor(s, 32);
    const float inv = 1.f / s;
    #pragma unroll
    for (int wt = 0; wt < 8; ++wt) {
        #pragma unroll
        for (int q = 0; q < 16; ++q) acc[wt][q] *= inv;
    }

    // ---- z GEMM + p writeback (tight burst; B from LDS only) ----
    float* prow = out_p + (size_t)row * (NB * NW) + (size_t)k * NW + hi * 8;
    f32x16 zacc[2];
    zacc[0] = {}; zacc[1] = {};
    #pragma unroll
    for (int ks = 0; ks < 16; ++ks) {
        const int wt = ks >> 1;
        const int q0 = (ks & 1) * 8;
        float v[8];
        #pragma unroll
        for (int i = 0; i < 4; ++i) {
            float a0 = acc[wt][q0 + i];
            float a1 = acc[wt][q0 + 4 + i];
            xch32(a0, a1, hi);
            v[i] = a0; v[4 + i] = a1;
        }
        *(f32x4*)(prow + ks * 16)     = f32x4{v[0], v[1], v[2], v[3]};
        *(f32x4*)(prow + ks * 16 + 4) = f32x4{v[4], v[5], v[6], v[7]};
        U8 pa;
        pa.u[0] = pku(v[0], v[1]); pa.u[1] = pku(v[2], v[3]);
        pa.u[2] = pku(v[4], v[5]); pa.u[3] = pku(v[6], v[7]);
        #pragma unroll
        for (int nt = 0; nt < 2; ++nt) {
            f16x8 bz = *(const f16x8*)&ctt[(nt * 32 + lr) * 256 + (((ks * 2 + hi) ^ (lr & 7))) * 8];
            zacc[nt] = __builtin_amdgcn_mfma_f32_32x32x16_f16(pa.v, bz, zacc[nt], 0, 0, 0);
        }
    }
    const int rbase = r0 + wid * 32;
    #pragma unroll
    for (int nt = 0; nt < 2; ++nt) {
        #pragma unroll
        for (int q = 0; q < 16; ++q) {
            int rr = (q & 3) + 8 * (q >> 2) + 4 * hi;
            out_z[(size_t)(rbase + rr) * DF + k * LW + nt * 32 + lr] = zacc[nt][q];
        }
    }
}

// ---------------------------------------------------------------------------
// MLP kernel: R15-verbatim. grid (BSZ*NB/128), block 256, LDS 37KB,
// bounds(256,4) -> 16 waves/CU (measured win). Launched FIRST this round:
// its f read (64MB) warms L3 for quant's latency-critical x loads.
// ---------------------------------------------------------------------------
__global__ __launch_bounds__(256, 4) void mlp_kernel(
    const float* __restrict__ f, const char* __restrict__ ws,
    const float* __restrict__ b1, const float* __restrict__ b2,
    float* __restrict__ out_lg)
{
    __shared__ _Float16 w1t[NW * LW];    // [h][l], chunk s at s^(h&7)
    __shared__ _Float16 w2t[8 * NW];     // [m][h], chunk c at c^m
    __shared__ float    b1s[NW];

    const _Float16* w1h = (const _Float16*)(ws + WS_W1H);
    const _Float16* w2h = (const _Float16*)(ws + WS_W2H);

    const int tid  = threadIdx.x;
    const int wid  = tid >> 6;
    const int lane = tid & 63;
    const int lr   = lane & 31;
    const int hi   = lane >> 5;
    const int m0   = blockIdx.x * 128;
    const int m    = m0 + wid * 32 + lr;      // this lane's f_split row

    // ---- staging ----
    #pragma unroll
    for (int it = 0; it < 8; ++it) {
        int i = it * 256 + tid;           // w1t chunk: h = i>>3, s = i&7
        int h = i >> 3, s = i & 7;
        f16x8 v = *(const f16x8*)(w1h + h * 64 + s * 8);
        *(f16x8*)&w1t[h * 64 + (s ^ (h & 7)) * 8] = v;
    }
    {
        int mm = tid >> 5, c = tid & 31;  // w2t: 256 chunks
        f16x8 v = *(const f16x8*)(w2h + mm * 256 + c * 8);
        *(f16x8*)&w2t[mm * 256 + (c ^ mm) * 8] = v;
    }
    b1s[tid] = b1[tid];
    __syncthreads();

    // ---- x fragment load ----
    float x_[32];
    {
        const float* fr = f + (size_t)m * LW + hi * 8;
        #pragma unroll
        for (int i = 0; i < 8; ++i)
            *(f32x4*)&x_[i * 4] = *(const f32x4*)(fr + (i >> 1) * 16 + (i & 1) * 4);
    }
    f16x8 bxh[4];
    #pragma unroll
    for (int ks = 0; ks < 4; ++ks) {
        U8 uh;
        #pragma unroll
        for (int mm = 0; mm < 4; ++mm)
            uh.u[mm] = pku(x_[ks * 8 + 2 * mm], x_[ks * 8 + 2 * mm + 1]);
        bxh[ks] = uh.v;
    }

    // ---- G1 (streaming per-ht) -> pack -> G2 ----
    f32x16 acc2 = {};
    #pragma unroll
    for (int ht = 0; ht < 8; ++ht) {
        f32x16 a1 = {};
        #pragma unroll
        for (int ks = 0; ks < 4; ++ks) {
            f16x8 a = *(const f16x8*)&w1t[(ht * 32 + lr) * 64 + (((ks * 2 + hi) ^ (lr & 7))) * 8];
            a1 = __builtin_amdgcn_mfma_f32_32x32x16_f16(a, bxh[ks], a1, 0, 0, 0);
        }
        float hv[16];
        #pragma unroll
        for (int g = 0; g < 4; ++g) {
            F4 b4; b4.v = *(const f32x4*)&b1s[ht * 32 + g * 8 + hi * 4];
            #pragma unroll
            for (int j = 0; j < 4; ++j) {
                int q = g * 4 + j;
                hv[q] = fmaxf(a1[q] + b4.a[j], 0.f);
            }
        }
        #pragma unroll
        for (int half = 0; half < 2; ++half) {
            const int ks = 2 * ht + half;
            const int q0 = half * 8;
            float v[8];
            #pragma unroll
            for (int i = 0; i < 4; ++i) {
                float a0 = hv[q0 + i];
                float a1v = hv[q0 + 4 + i];
                xch32(a0, a1v, hi);
                v[i] = a0; v[4 + i] = a1v;
            }
            U8 hb;
            hb.u[0] = pku(v[0], v[1]); hb.u[1] = pku(v[2], v[3]);
            hb.u[2] = pku(v[4], v[5]); hb.u[3] = pku(v[6], v[7]);
            f16x8 aw2 = *(const f16x8*)&w2t[(lr & 7) * 256 + (((ks * 2 + hi) ^ (lr & 7))) * 8];
            acc2 = __builtin_amdgcn_mfma_f32_32x32x16_f16(aw2, hb.v, acc2, 0, 0, 0);
        }
    }

    // ---- log_softmax over 8 classes (regs q=0..3 hold classes q+4*hi) ----
    F4 b2v; b2v.v = *(const f32x4*)(b2 + hi * 4);
    float lg[4];
    #pragma unroll
    for (int q = 0; q < 4; ++q) lg[q] = acc2[q] + b2v.a[q];
    float mm = fmaxf(fmaxf(lg[0], lg[1]), fmaxf(lg[2], lg[3]));
    mm = fmaxf(mm, __shfl_xor(mm, 32));
    float se = 0.f;
    #pragma unroll
    for (int q = 0; q < 4; ++q) se += __builtin_amdgcn_exp2f((lg[q] - mm) * LOG2E);
    se += __shfl_xor(se, 32);
    float lse = mm + __builtin_amdgcn_logf(se) * LN2;
    *(f32x4*)(out_lg + (size_t)m * 8 + hi * 4) =
        f32x4{lg[0] - lse, lg[1] - lse, lg[2] - lse, lg[3] - lse};
}

extern "C" void kernel_launch(void* const* d_in, const int* in_sizes, int n_in,
                              void* d_out, int out_size, void* d_ws, size_t ws_size,
                              hipStream_t stream) {
    const float* f  = (const float*)d_in[0];
    const float* cb = (const float*)d_in[1];
    const float* W1 = (const float*)d_in[2];
    const float* b1 = (const float*)d_in[3];
    const float* W2 = (const float*)d_in[4];
    const float* b2 = (const float*)d_in[5];

    float* out    = (float*)d_out;
    float* out_f  = out;
    float* out_z  = out_f + (size_t)BSZ * DF;
    float* out_p  = out_z + (size_t)BSZ * DF;
    float* out_lg = out_p + (size_t)BSZ * NB * NW;

    hipLaunchKernelGGL(prep_kernel, dim3(9), dim3(256), 0, stream,
                       cb, W1, W2, (char*)d_ws);
    // mlp first: warms L3 with f (64MB) for quant's latency-critical x loads.
    hipLaunchKernelGGL(mlp_kernel, dim3(BSZ * NB / 128), dim3(256), 0, stream,
                       f, (const char*)d_ws, b1, b2, out_lg);
    hipLaunchKernelGGL(quant_kernel, dim3(BSZ / 128, NB), dim3(256), 0, stream,
                       f, (const char*)d_ws, out_f, out_z, out_p);
}